// Round 1
// baseline (7147.117 us; speedup 1.0000x reference)
//
#include <hip/hip_runtime.h>

#define N_NODES 100000
#define N_EDGES 1600000
#define DH 128
#define DOUT 64
#define EPS 1e-6f

// ---------------- GEMM: Y[nrows, COLS] = X[nrows,128] @ W[128,COLS] + b ----------------
template <int COLS>
__global__ __launch_bounds__(256) void gemm_kernel(const float* __restrict__ X,
                                                   const float* __restrict__ W,
                                                   const float* __restrict__ bias,
                                                   float* __restrict__ Y, int nrows) {
    constexpr int K = 128;
    constexpr int COLG = COLS / 8;    // threads covering the column dim (8 cols each)
    constexpr int ROWG = 256 / COLG;  // row groups per block
    constexpr int RPT = 64 / ROWG;    // rows per thread (block tile = 64 rows)

    __shared__ float wlds[K * COLS];
    __shared__ float xlds[64][K + 1];  // +1 pad: avoids same-bank broadcast-group conflicts

    const int tid = threadIdx.x;
    const int row0 = blockIdx.x * 64;

    // stage W (K*COLS floats) as float4
    constexpr int WVEC = K * COLS / 4;
    for (int i = tid; i < WVEC; i += 256) {
        reinterpret_cast<float4*>(wlds)[i] = reinterpret_cast<const float4*>(W)[i];
    }
    // stage X tile (64 x 128)
    for (int i = tid; i < 64 * (K / 4); i += 256) {
        int r = i / (K / 4);
        int c4 = i % (K / 4);
        float4 v = make_float4(0.f, 0.f, 0.f, 0.f);
        if (row0 + r < nrows)
            v = reinterpret_cast<const float4*>(X + (size_t)(row0 + r) * K)[c4];
        xlds[r][c4 * 4 + 0] = v.x;
        xlds[r][c4 * 4 + 1] = v.y;
        xlds[r][c4 * 4 + 2] = v.z;
        xlds[r][c4 * 4 + 3] = v.w;
    }
    __syncthreads();

    const int colg = tid % COLG;
    const int rowg = tid / COLG;
    const int c0 = colg * 8;
    const int r0 = rowg * RPT;

    float acc[RPT][8];
#pragma unroll
    for (int i = 0; i < RPT; ++i)
#pragma unroll
        for (int j = 0; j < 8; ++j) acc[i][j] = 0.f;

    for (int k = 0; k < K; ++k) {
        float4 w0 = *reinterpret_cast<const float4*>(&wlds[k * COLS + c0]);
        float4 w1 = *reinterpret_cast<const float4*>(&wlds[k * COLS + c0 + 4]);
#pragma unroll
        for (int i = 0; i < RPT; ++i) {
            float xv = xlds[r0 + i][k];
            acc[i][0] += xv * w0.x;
            acc[i][1] += xv * w0.y;
            acc[i][2] += xv * w0.z;
            acc[i][3] += xv * w0.w;
            acc[i][4] += xv * w1.x;
            acc[i][5] += xv * w1.y;
            acc[i][6] += xv * w1.z;
            acc[i][7] += xv * w1.w;
        }
    }

    float bv[8];
#pragma unroll
    for (int j = 0; j < 8; ++j) bv[j] = bias[c0 + j];

#pragma unroll
    for (int i = 0; i < RPT; ++i) {
        int row = row0 + r0 + i;
        if (row < nrows) {
            float4 o0 = make_float4(acc[i][0] + bv[0], acc[i][1] + bv[1], acc[i][2] + bv[2],
                                    acc[i][3] + bv[3]);
            float4 o1 = make_float4(acc[i][4] + bv[4], acc[i][5] + bv[5], acc[i][6] + bv[6],
                                    acc[i][7] + bv[7]);
            float4* yp = reinterpret_cast<float4*>(Y + (size_t)row * COLS + c0);
            yp[0] = o0;
            yp[1] = o1;
        }
    }
}

// ---------------- edge scatter: out[dst] += w * H[src], atomics ----------------
template <int DF>
__global__ __launch_bounds__(256) void scatter_kernel(const float* __restrict__ H,
                                                      const int* __restrict__ src,
                                                      const int* __restrict__ dst,
                                                      const float* __restrict__ ew,
                                                      float* __restrict__ out) {
    constexpr int F4 = DF / 4;
    long long idx = (long long)blockIdx.x * blockDim.x + threadIdx.x;
    const long long total = (long long)N_EDGES * F4;
    const long long stride = (long long)gridDim.x * blockDim.x;
    for (; idx < total; idx += stride) {
        int e = (int)(idx / F4);
        int f = (int)(idx % F4);
        int s = src[e];
        int d = dst[e];
        float w = ew[e];
        float4 h = reinterpret_cast<const float4*>(H + (size_t)s * DF)[f];
        float* o = out + (size_t)d * DF + f * 4;
        atomicAdd(o + 0, w * h.x);
        atomicAdd(o + 1, w * h.y);
        atomicAdd(o + 2, w * h.z);
        atomicAdd(o + 3, w * h.w);
    }
}

// ---------------- PairNorm stats: colsum[128], sumsq = sum(a^2) ----------------
__global__ __launch_bounds__(256) void stats_kernel(const float* __restrict__ A,
                                                    float* __restrict__ colsum,
                                                    float* __restrict__ sumsq) {
    const int c = threadIdx.x & 127;
    const int rsub = threadIdx.x >> 7;
    float cs = 0.f, sq = 0.f;
    for (int r = blockIdx.x * 2 + rsub; r < N_NODES; r += gridDim.x * 2) {
        float v = A[(size_t)r * DH + c];
        cs += v;
        sq += v * v;
    }
    atomicAdd(&colsum[c], cs);
#pragma unroll
    for (int off = 32; off; off >>= 1) sq += __shfl_down(sq, off, 64);
    if ((threadIdx.x & 63) == 0) atomicAdd(sumsq, sq);
}

__global__ void finalize_stats(const float* __restrict__ colsum, const float* __restrict__ sumsq,
                               float* __restrict__ mu, float* __restrict__ inv) {
    const int t = threadIdx.x;  // 128 threads
    float m = colsum[t] / (float)N_NODES;
    mu[t] = m;
    float v = m * m;
    __shared__ float part[2];
#pragma unroll
    for (int off = 32; off; off >>= 1) v += __shfl_down(v, off, 64);
    if ((t & 63) == 0) part[t >> 6] = v;
    __syncthreads();
    if (t == 0) {
        float musq = part[0] + part[1];
        float s = (sumsq[0] - (float)N_NODES * musq) / (float)N_NODES;
        inv[0] = rsqrtf(EPS + s);
    }
}

// ---------------- apply: out = relu((A - mu) * inv) + resid ----------------
__global__ __launch_bounds__(256) void apply_pn(const float* __restrict__ A,
                                                const float* __restrict__ mu,
                                                const float* __restrict__ inv,
                                                const float* __restrict__ resid,
                                                float* __restrict__ out) {
    const int total = N_NODES * (DH / 4);
    int idx = blockIdx.x * blockDim.x + threadIdx.x;
    if (idx >= total) return;
    const float s = inv[0];
    const int c4 = idx & 31;  // DH/4 = 32
    float4 a = reinterpret_cast<const float4*>(A)[idx];
    float4 m = reinterpret_cast<const float4*>(mu)[c4];
    float4 r = make_float4(0.f, 0.f, 0.f, 0.f);
    if (resid) r = reinterpret_cast<const float4*>(resid)[idx];
    float4 o;
    o.x = fmaxf((a.x - m.x) * s, 0.f) + r.x;
    o.y = fmaxf((a.y - m.y) * s, 0.f) + r.y;
    o.z = fmaxf((a.z - m.z) * s, 0.f) + r.z;
    o.w = fmaxf((a.w - m.w) * s, 0.f) + r.w;
    reinterpret_cast<float4*>(out)[idx] = o;
}

extern "C" void kernel_launch(void* const* d_in, const int* in_sizes, int n_in,
                              void* d_out, int out_size, void* d_ws, size_t ws_size,
                              hipStream_t stream) {
    const float* x = (const float*)d_in[0];
    const int* edge_index = (const int*)d_in[1];
    const float* ew = (const float*)d_in[2];
    const float* W0 = (const float*)d_in[3];
    const float* b0 = (const float*)d_in[4];
    const float* W1 = (const float*)d_in[5];
    const float* b1 = (const float*)d_in[6];
    const float* Wout = (const float*)d_in[7];
    const float* bout = (const float*)d_in[8];

    const int* src = edge_index;            // edge_index[0]
    const int* dst = edge_index + N_EDGES;  // edge_index[1]
    float* out = (float*)d_out;

    float* A = (float*)d_ws;                     // N*128  (H / X2 / ...)
    float* B = A + (size_t)N_NODES * DH;         // N*128  (AGG)
    float* C = B + (size_t)N_NODES * DH;         // N*128  (X1 / HOUT)
    float* stats = C + (size_t)N_NODES * DH;
    float* colsum = stats;       // 128
    float* sumsq = stats + 128;  // 1
    float* mu = stats + 129;     // 128
    float* inv = stats + 257;    // 1

    const int gemm_grid = (N_NODES + 63) / 64;
    const int apply_grid = (N_NODES * (DH / 4) + 255) / 256;

    // ---- Layer 1: H = x@W0+b0; AGG = scatter(H); X1 = relu(pn(AGG)) ----
    gemm_kernel<128><<<gemm_grid, 256, 0, stream>>>(x, W0, b0, A, N_NODES);
    hipMemsetAsync(B, 0, (size_t)N_NODES * DH * sizeof(float), stream);
    scatter_kernel<128><<<8192, 256, 0, stream>>>(A, src, dst, ew, B);
    hipMemsetAsync(stats, 0, 129 * sizeof(float), stream);
    stats_kernel<<<1024, 256, 0, stream>>>(B, colsum, sumsq);
    finalize_stats<<<1, 128, 0, stream>>>(colsum, sumsq, mu, inv);
    apply_pn<<<apply_grid, 256, 0, stream>>>(B, mu, inv, nullptr, C);

    // ---- Layer 2: H = X1@W1+b1; AGG = scatter(H); X2 = relu(pn(AGG)) + X1 ----
    gemm_kernel<128><<<gemm_grid, 256, 0, stream>>>(C, W1, b1, A, N_NODES);
    hipMemsetAsync(B, 0, (size_t)N_NODES * DH * sizeof(float), stream);
    scatter_kernel<128><<<8192, 256, 0, stream>>>(A, src, dst, ew, B);
    hipMemsetAsync(stats, 0, 129 * sizeof(float), stream);
    stats_kernel<<<1024, 256, 0, stream>>>(B, colsum, sumsq);
    finalize_stats<<<1, 128, 0, stream>>>(colsum, sumsq, mu, inv);
    apply_pn<<<apply_grid, 256, 0, stream>>>(B, mu, inv, C, A);  // X2 -> A

    // ---- Output layer: HOUT = X2@Wout+bout; out = scatter64(HOUT) ----
    gemm_kernel<64><<<gemm_grid, 256, 0, stream>>>(A, Wout, bout, C, N_NODES);
    hipMemsetAsync(out, 0, (size_t)N_NODES * DOUT * sizeof(float), stream);
    scatter_kernel<64><<<8192, 256, 0, stream>>>(C, src, dst, ew, out);
}

// Round 2
// 1141.097 us; speedup vs baseline: 6.2634x; 6.2634x over previous
//
#include <hip/hip_runtime.h>

#define N_NODES 100000
#define N_EDGES 1600000
#define DH 128
#define DOUT 64
#define EPS 1e-6f

// ---------------- GEMM: Y[nrows, COLS] = X[nrows,128] @ W[128,COLS] + b ----------------
template <int COLS>
__global__ __launch_bounds__(256) void gemm_kernel(const float* __restrict__ X,
                                                   const float* __restrict__ W,
                                                   const float* __restrict__ bias,
                                                   float* __restrict__ Y, int nrows) {
    constexpr int K = 128;
    constexpr int COLG = COLS / 8;    // threads covering the column dim (8 cols each)
    constexpr int ROWG = 256 / COLG;  // row groups per block
    constexpr int RPT = 64 / ROWG;    // rows per thread (block tile = 64 rows)

    __shared__ float wlds[K * COLS];
    __shared__ float xlds[64][K + 1];

    const int tid = threadIdx.x;
    const int row0 = blockIdx.x * 64;

    constexpr int WVEC = K * COLS / 4;
    for (int i = tid; i < WVEC; i += 256) {
        reinterpret_cast<float4*>(wlds)[i] = reinterpret_cast<const float4*>(W)[i];
    }
    for (int i = tid; i < 64 * (K / 4); i += 256) {
        int r = i / (K / 4);
        int c4 = i % (K / 4);
        float4 v = make_float4(0.f, 0.f, 0.f, 0.f);
        if (row0 + r < nrows)
            v = reinterpret_cast<const float4*>(X + (size_t)(row0 + r) * K)[c4];
        xlds[r][c4 * 4 + 0] = v.x;
        xlds[r][c4 * 4 + 1] = v.y;
        xlds[r][c4 * 4 + 2] = v.z;
        xlds[r][c4 * 4 + 3] = v.w;
    }
    __syncthreads();

    const int colg = tid % COLG;
    const int rowg = tid / COLG;
    const int c0 = colg * 8;
    const int r0 = rowg * RPT;

    float acc[RPT][8];
#pragma unroll
    for (int i = 0; i < RPT; ++i)
#pragma unroll
        for (int j = 0; j < 8; ++j) acc[i][j] = 0.f;

    for (int k = 0; k < K; ++k) {
        float4 w0 = *reinterpret_cast<const float4*>(&wlds[k * COLS + c0]);
        float4 w1 = *reinterpret_cast<const float4*>(&wlds[k * COLS + c0 + 4]);
#pragma unroll
        for (int i = 0; i < RPT; ++i) {
            float xv = xlds[r0 + i][k];
            acc[i][0] += xv * w0.x;
            acc[i][1] += xv * w0.y;
            acc[i][2] += xv * w0.z;
            acc[i][3] += xv * w0.w;
            acc[i][4] += xv * w1.x;
            acc[i][5] += xv * w1.y;
            acc[i][6] += xv * w1.z;
            acc[i][7] += xv * w1.w;
        }
    }

    float bv[8];
#pragma unroll
    for (int j = 0; j < 8; ++j) bv[j] = bias[c0 + j];

#pragma unroll
    for (int i = 0; i < RPT; ++i) {
        int row = row0 + r0 + i;
        if (row < nrows) {
            float4 o0 = make_float4(acc[i][0] + bv[0], acc[i][1] + bv[1], acc[i][2] + bv[2],
                                    acc[i][3] + bv[3]);
            float4 o1 = make_float4(acc[i][4] + bv[4], acc[i][5] + bv[5], acc[i][6] + bv[6],
                                    acc[i][7] + bv[7]);
            float4* yp = reinterpret_cast<float4*>(Y + (size_t)row * COLS + c0);
            yp[0] = o0;
            yp[1] = o1;
        }
    }
}

// ---------------- CSR build ----------------
__global__ __launch_bounds__(256) void hist_kernel(const int* __restrict__ dst,
                                                   int* __restrict__ counts) {
    int e = blockIdx.x * blockDim.x + threadIdx.x;
    const int stride = gridDim.x * blockDim.x;
    for (; e < N_EDGES; e += stride) atomicAdd(&counts[dst[e]], 1);
}

// single-block inclusive scan over counts -> rowptr[1..N]; rowptr[0]=0
__global__ __launch_bounds__(1024) void scan_kernel(const int* __restrict__ counts,
                                                    int* __restrict__ rowptr) {
    __shared__ int wsum[16];
    const int tid = threadIdx.x;
    const int lane = tid & 63;
    const int w = tid >> 6;
    int offset = 0;
    if (tid == 0) rowptr[0] = 0;
    for (int base = 0; base < N_NODES; base += 1024) {
        int i = base + tid;
        int v = (i < N_NODES) ? counts[i] : 0;
        int incl = v;
#pragma unroll
        for (int d = 1; d < 64; d <<= 1) {
            int t = __shfl_up(incl, d, 64);
            if (lane >= d) incl += t;
        }
        if (lane == 63) wsum[w] = incl;
        __syncthreads();
        if (w == 0 && lane < 16) {
            int t = wsum[lane];
#pragma unroll
            for (int d = 1; d < 16; d <<= 1) {
                int u = __shfl_up(t, d, 64);
                if (lane >= d) t += u;
            }
            wsum[lane] = t;
        }
        __syncthreads();
        int waveoff = (w == 0) ? 0 : wsum[w - 1];
        int chunk_total = wsum[15];
        if (i < N_NODES) rowptr[i + 1] = offset + waveoff + incl;
        offset += chunk_total;
        __syncthreads();
    }
}

__global__ __launch_bounds__(256) void bucket_kernel(const int* __restrict__ src,
                                                     const int* __restrict__ dst,
                                                     const float* __restrict__ ew,
                                                     const int* __restrict__ rowptr,
                                                     int* __restrict__ fill,
                                                     int* __restrict__ es,
                                                     float* __restrict__ wsorted) {
    int e = blockIdx.x * blockDim.x + threadIdx.x;
    const int stride = gridDim.x * blockDim.x;
    for (; e < N_EDGES; e += stride) {
        int d = dst[e];
        int pos = atomicAdd(&fill[d], 1);
        int idx = rowptr[d] + pos;
        es[idx] = src[e];
        wsorted[idx] = ew[e];
    }
}

// ---------------- gather aggregation: one wave per dst node ----------------
__global__ __launch_bounds__(256) void agg128_kernel(const float* __restrict__ H,
                                                     const int* __restrict__ rowptr,
                                                     const int* __restrict__ es,
                                                     const float* __restrict__ wsorted,
                                                     float* __restrict__ out) {
    const int node = blockIdx.x * 4 + (threadIdx.x >> 6);
    const int lane = threadIdx.x & 63;
    if (node >= N_NODES) return;
    const int beg = rowptr[node];
    const int end = rowptr[node + 1];
    float2 acc = make_float2(0.f, 0.f);
    for (int k = beg; k < end; ++k) {
        int s = es[k];
        float w = wsorted[k];
        float2 h = reinterpret_cast<const float2*>(H + (size_t)s * DH)[lane];
        acc.x += w * h.x;
        acc.y += w * h.y;
    }
    reinterpret_cast<float2*>(out + (size_t)node * DH)[lane] = acc;
}

__global__ __launch_bounds__(256) void agg64_kernel(const float* __restrict__ H,
                                                    const int* __restrict__ rowptr,
                                                    const int* __restrict__ es,
                                                    const float* __restrict__ wsorted,
                                                    float* __restrict__ out) {
    const int node = blockIdx.x * 4 + (threadIdx.x >> 6);
    const int lane = threadIdx.x & 63;
    if (node >= N_NODES) return;
    const int beg = rowptr[node];
    const int end = rowptr[node + 1];
    float acc = 0.f;
    for (int k = beg; k < end; ++k) {
        int s = es[k];
        float w = wsorted[k];
        acc += w * H[(size_t)s * DOUT + lane];
    }
    out[(size_t)node * DOUT + lane] = acc;
}

// ---------------- PairNorm stats ----------------
__global__ __launch_bounds__(256) void stats_kernel(const float* __restrict__ A,
                                                    float* __restrict__ colsum,
                                                    float* __restrict__ sumsq) {
    const int c = threadIdx.x & 127;
    const int rsub = threadIdx.x >> 7;
    float cs = 0.f, sq = 0.f;
    for (int r = blockIdx.x * 2 + rsub; r < N_NODES; r += gridDim.x * 2) {
        float v = A[(size_t)r * DH + c];
        cs += v;
        sq += v * v;
    }
    atomicAdd(&colsum[c], cs);
#pragma unroll
    for (int off = 32; off; off >>= 1) sq += __shfl_down(sq, off, 64);
    if ((threadIdx.x & 63) == 0) atomicAdd(sumsq, sq);
}

__global__ void finalize_stats(const float* __restrict__ colsum, const float* __restrict__ sumsq,
                               float* __restrict__ mu, float* __restrict__ inv) {
    const int t = threadIdx.x;  // 128 threads
    float m = colsum[t] / (float)N_NODES;
    mu[t] = m;
    float v = m * m;
    __shared__ float part[2];
#pragma unroll
    for (int off = 32; off; off >>= 1) v += __shfl_down(v, off, 64);
    if ((t & 63) == 0) part[t >> 6] = v;
    __syncthreads();
    if (t == 0) {
        float musq = part[0] + part[1];
        float s = (sumsq[0] - (float)N_NODES * musq) / (float)N_NODES;
        inv[0] = rsqrtf(EPS + s);
    }
}

// ---------------- apply: out = relu((A - mu) * inv) + resid ----------------
__global__ __launch_bounds__(256) void apply_pn(const float* __restrict__ A,
                                                const float* __restrict__ mu,
                                                const float* __restrict__ inv,
                                                const float* __restrict__ resid,
                                                float* __restrict__ out) {
    const int total = N_NODES * (DH / 4);
    int idx = blockIdx.x * blockDim.x + threadIdx.x;
    if (idx >= total) return;
    const float s = inv[0];
    const int c4 = idx & 31;
    float4 a = reinterpret_cast<const float4*>(A)[idx];
    float4 m = reinterpret_cast<const float4*>(mu)[c4];
    float4 r = make_float4(0.f, 0.f, 0.f, 0.f);
    if (resid) r = reinterpret_cast<const float4*>(resid)[idx];
    float4 o;
    o.x = fmaxf((a.x - m.x) * s, 0.f) + r.x;
    o.y = fmaxf((a.y - m.y) * s, 0.f) + r.y;
    o.z = fmaxf((a.z - m.z) * s, 0.f) + r.z;
    o.w = fmaxf((a.w - m.w) * s, 0.f) + r.w;
    reinterpret_cast<float4*>(out)[idx] = o;
}

extern "C" void kernel_launch(void* const* d_in, const int* in_sizes, int n_in,
                              void* d_out, int out_size, void* d_ws, size_t ws_size,
                              hipStream_t stream) {
    const float* x = (const float*)d_in[0];
    const int* edge_index = (const int*)d_in[1];
    const float* ew = (const float*)d_in[2];
    const float* W0 = (const float*)d_in[3];
    const float* b0 = (const float*)d_in[4];
    const float* W1 = (const float*)d_in[5];
    const float* b1 = (const float*)d_in[6];
    const float* Wout = (const float*)d_in[7];
    const float* bout = (const float*)d_in[8];

    const int* src = edge_index;            // edge_index[0]
    const int* dst = edge_index + N_EDGES;  // edge_index[1]
    float* out = (float*)d_out;

    float* A = (float*)d_ws;              // N*128
    float* B = A + (size_t)N_NODES * DH;  // N*128
    float* C = B + (size_t)N_NODES * DH;  // N*128
    float* stats = C + (size_t)N_NODES * DH;
    float* colsum = stats;       // 128
    float* sumsq = stats + 128;  // 1
    float* mu = stats + 129;     // 128
    float* inv = stats + 257;    // 1
    int* counts = (int*)(stats + 258);
    int* rowptr = counts + N_NODES;       // N+1
    int* fill = rowptr + N_NODES + 1;     // N
    int* es = fill + N_NODES;             // E
    float* wsorted = (float*)(es + N_EDGES);  // E

    const int gemm_grid = (N_NODES + 63) / 64;
    const int apply_grid = (N_NODES * (DH / 4) + 255) / 256;
    const int agg_grid = (N_NODES + 3) / 4;

    // ---- CSR build (dst-ordered) ----
    hipMemsetAsync(counts, 0, (size_t)(2 * N_NODES + 1) * sizeof(int) + 129 * sizeof(float),
                   stream);  // counts + rowptr... (contiguous: counts,rowptr,fill)
    // note: counts..fill are contiguous: N + (N+1) + N ints
    hipMemsetAsync(fill, 0, (size_t)N_NODES * sizeof(int), stream);
    hist_kernel<<<2048, 256, 0, stream>>>(dst, counts);
    scan_kernel<<<1, 1024, 0, stream>>>(counts, rowptr);
    bucket_kernel<<<2048, 256, 0, stream>>>(src, dst, ew, rowptr, fill, es, wsorted);

    // ---- Layer 1: H = x@W0+b0; AGG = gather(H); X1 = relu(pn(AGG)) ----
    gemm_kernel<128><<<gemm_grid, 256, 0, stream>>>(x, W0, b0, A, N_NODES);
    agg128_kernel<<<agg_grid, 256, 0, stream>>>(A, rowptr, es, wsorted, B);
    hipMemsetAsync(stats, 0, 129 * sizeof(float), stream);
    stats_kernel<<<1024, 256, 0, stream>>>(B, colsum, sumsq);
    finalize_stats<<<1, 128, 0, stream>>>(colsum, sumsq, mu, inv);
    apply_pn<<<apply_grid, 256, 0, stream>>>(B, mu, inv, nullptr, C);

    // ---- Layer 2 ----
    gemm_kernel<128><<<gemm_grid, 256, 0, stream>>>(C, W1, b1, A, N_NODES);
    agg128_kernel<<<agg_grid, 256, 0, stream>>>(A, rowptr, es, wsorted, B);
    hipMemsetAsync(stats, 0, 129 * sizeof(float), stream);
    stats_kernel<<<1024, 256, 0, stream>>>(B, colsum, sumsq);
    finalize_stats<<<1, 128, 0, stream>>>(colsum, sumsq, mu, inv);
    apply_pn<<<apply_grid, 256, 0, stream>>>(B, mu, inv, C, A);  // X2 -> A

    // ---- Output layer ----
    gemm_kernel<64><<<gemm_grid, 256, 0, stream>>>(A, Wout, bout, C, N_NODES);
    agg64_kernel<<<agg_grid, 256, 0, stream>>>(C, rowptr, es, wsorted, out);
}

// Round 3
// 795.085 us; speedup vs baseline: 8.9891x; 1.4352x over previous
//
#include <hip/hip_runtime.h>

#define N_NODES 100000
#define N_EDGES 1600000
#define DH 128
#define DOUT 64
#define EPS 1e-6f

__device__ inline unsigned bfround(float f) {  // f32 -> bf16 bits, round-nearest-even
    unsigned u = __float_as_uint(f);
    return (u + 0x7fffu + ((u >> 16) & 1u)) >> 16;
}
__device__ inline unsigned pack2(float a, float b) { return bfround(a) | (bfround(b) << 16); }

// ---------------- GEMM: Y[nrows, COLS] = f(X)[nrows,128] @ W[128,COLS] + b ----------------
// PN=0: f(X)=Xa.  PN=1: f(X)=relu((Xa-muA)*invA).  PN=2: f(X)=relu((Xa-muA)*invA)+relu((Xb-muB)*invB)
// OUTBF: write packed bf16 (uint per col-pair) instead of f32.
template <int COLS, int PN, bool OUTBF>
__global__ __launch_bounds__(256) void gemm_kernel(const float* __restrict__ Xa,
                                                   const float* __restrict__ muA,
                                                   const float* __restrict__ invA,
                                                   const float* __restrict__ Xb,
                                                   const float* __restrict__ muB,
                                                   const float* __restrict__ invB,
                                                   const float* __restrict__ W,
                                                   const float* __restrict__ bias,
                                                   void* __restrict__ Yv, int nrows) {
    constexpr int K = 128;
    constexpr int BK = 64;            // K-chunk
    constexpr int COLG = COLS / 8;    // threads covering column dim (8 cols each)
    constexpr int ROWG = 256 / COLG;  // row groups per block
    constexpr int RPT = 64 / ROWG;    // rows per thread

    __shared__ float wlds[BK * COLS];
    __shared__ float xlds[64][BK + 1];

    const int tid = threadIdx.x;
    const int row0 = blockIdx.x * 64;

    const float sA = (PN >= 1) ? invA[0] : 0.f;
    const float sB = (PN == 2) ? invB[0] : 0.f;

    const int colg = tid % COLG;
    const int rowg = tid / COLG;
    const int c0 = colg * 8;
    const int r0 = rowg * RPT;

    float acc[RPT][8];
#pragma unroll
    for (int i = 0; i < RPT; ++i)
#pragma unroll
        for (int j = 0; j < 8; ++j) acc[i][j] = 0.f;

    for (int kb = 0; kb < K; kb += BK) {
        // stage W chunk [kb..kb+BK) x COLS
        constexpr int WVEC = BK * COLS / 4;
        for (int i = tid; i < WVEC; i += 256) {
            int kr = i / (COLS / 4);
            int c4 = i % (COLS / 4);
            reinterpret_cast<float4*>(wlds)[i] =
                reinterpret_cast<const float4*>(W)[(size_t)(kb + kr) * (COLS / 4) + c4];
        }
        // stage X tile: 64 rows x BK cols, with fused pairnorm/relu/residual
        for (int i = tid; i < 64 * (BK / 4); i += 256) {
            int r = i / (BK / 4);
            int c4 = i % (BK / 4);
            int col4 = kb / 4 + c4;  // global float4 col index
            float4 v = make_float4(0.f, 0.f, 0.f, 0.f);
            if (row0 + r < nrows) {
                v = reinterpret_cast<const float4*>(Xa + (size_t)(row0 + r) * K)[col4];
                if constexpr (PN >= 1) {
                    float4 m = reinterpret_cast<const float4*>(muA)[col4];
                    v.x = fmaxf((v.x - m.x) * sA, 0.f);
                    v.y = fmaxf((v.y - m.y) * sA, 0.f);
                    v.z = fmaxf((v.z - m.z) * sA, 0.f);
                    v.w = fmaxf((v.w - m.w) * sA, 0.f);
                }
                if constexpr (PN == 2) {
                    float4 v2 = reinterpret_cast<const float4*>(Xb + (size_t)(row0 + r) * K)[col4];
                    float4 m2 = reinterpret_cast<const float4*>(muB)[col4];
                    v.x += fmaxf((v2.x - m2.x) * sB, 0.f);
                    v.y += fmaxf((v2.y - m2.y) * sB, 0.f);
                    v.z += fmaxf((v2.z - m2.z) * sB, 0.f);
                    v.w += fmaxf((v2.w - m2.w) * sB, 0.f);
                }
            }
            xlds[r][c4 * 4 + 0] = v.x;
            xlds[r][c4 * 4 + 1] = v.y;
            xlds[r][c4 * 4 + 2] = v.z;
            xlds[r][c4 * 4 + 3] = v.w;
        }
        __syncthreads();

        for (int k = 0; k < BK; ++k) {
            float4 w0 = *reinterpret_cast<const float4*>(&wlds[k * COLS + c0]);
            float4 w1 = *reinterpret_cast<const float4*>(&wlds[k * COLS + c0 + 4]);
#pragma unroll
            for (int i = 0; i < RPT; ++i) {
                float xv = xlds[r0 + i][k];
                acc[i][0] += xv * w0.x;
                acc[i][1] += xv * w0.y;
                acc[i][2] += xv * w0.z;
                acc[i][3] += xv * w0.w;
                acc[i][4] += xv * w1.x;
                acc[i][5] += xv * w1.y;
                acc[i][6] += xv * w1.z;
                acc[i][7] += xv * w1.w;
            }
        }
        __syncthreads();
    }

    float bv[8];
#pragma unroll
    for (int j = 0; j < 8; ++j) bv[j] = bias[c0 + j];

#pragma unroll
    for (int i = 0; i < RPT; ++i) {
        int row = row0 + r0 + i;
        if (row < nrows) {
#pragma unroll
            for (int j = 0; j < 8; ++j) acc[i][j] += bv[j];
            if constexpr (OUTBF) {
                uint4 q;
                q.x = pack2(acc[i][0], acc[i][1]);
                q.y = pack2(acc[i][2], acc[i][3]);
                q.z = pack2(acc[i][4], acc[i][5]);
                q.w = pack2(acc[i][6], acc[i][7]);
                *reinterpret_cast<uint4*>((unsigned*)Yv + ((size_t)row * COLS + c0) / 2) = q;
            } else {
                float4 o0 = make_float4(acc[i][0], acc[i][1], acc[i][2], acc[i][3]);
                float4 o1 = make_float4(acc[i][4], acc[i][5], acc[i][6], acc[i][7]);
                float4* yp = reinterpret_cast<float4*>((float*)Yv + (size_t)row * COLS + c0);
                yp[0] = o0;
                yp[1] = o1;
            }
        }
    }
}

// ---------------- CSR build ----------------
__global__ __launch_bounds__(256) void hist_kernel(const int* __restrict__ dst,
                                                   int* __restrict__ counts) {
    int e = blockIdx.x * blockDim.x + threadIdx.x;
    const int stride = gridDim.x * blockDim.x;
    for (; e < N_EDGES; e += stride) atomicAdd(&counts[dst[e]], 1);
}

__global__ __launch_bounds__(1024) void scan_kernel(const int* __restrict__ counts,
                                                    int* __restrict__ rowptr) {
    __shared__ int wsum[16];
    const int tid = threadIdx.x;
    const int lane = tid & 63;
    const int w = tid >> 6;
    int offset = 0;
    if (tid == 0) rowptr[0] = 0;
    for (int base = 0; base < N_NODES; base += 1024) {
        int i = base + tid;
        int v = (i < N_NODES) ? counts[i] : 0;
        int incl = v;
#pragma unroll
        for (int d = 1; d < 64; d <<= 1) {
            int t = __shfl_up(incl, d, 64);
            if (lane >= d) incl += t;
        }
        if (lane == 63) wsum[w] = incl;
        __syncthreads();
        if (w == 0 && lane < 16) {
            int t = wsum[lane];
#pragma unroll
            for (int d = 1; d < 16; d <<= 1) {
                int u = __shfl_up(t, d, 64);
                if (lane >= d) t += u;
            }
            wsum[lane] = t;
        }
        __syncthreads();
        int waveoff = (w == 0) ? 0 : wsum[w - 1];
        int chunk_total = wsum[15];
        if (i < N_NODES) rowptr[i + 1] = offset + waveoff + incl;
        offset += chunk_total;
        __syncthreads();
    }
}

__global__ __launch_bounds__(256) void bucket_kernel(const int* __restrict__ src,
                                                     const int* __restrict__ dst,
                                                     const float* __restrict__ ew,
                                                     const int* __restrict__ rowptr,
                                                     int* __restrict__ fill,
                                                     int2* __restrict__ em) {
    int e = blockIdx.x * blockDim.x + threadIdx.x;
    const int stride = gridDim.x * blockDim.x;
    for (; e < N_EDGES; e += stride) {
        int d = dst[e];
        int pos = atomicAdd(&fill[d], 1);
        em[rowptr[d] + pos] = make_int2(src[e], __float_as_int(ew[e]));
    }
}

// ---------------- gather aggregation (bf16 H, 128 cols): one wave per dst node ----------------
__global__ __launch_bounds__(256) void agg128b_kernel(const unsigned* __restrict__ Hb,
                                                      const int* __restrict__ rowptr,
                                                      const int2* __restrict__ em,
                                                      float* __restrict__ B) {
    const int node = blockIdx.x * 4 + (threadIdx.x >> 6);  // grid covers exactly N
    const int lane = threadIdx.x & 63;
    const int beg = rowptr[node];
    const int end = rowptr[node + 1];
    float2 acc = make_float2(0.f, 0.f);
    for (int c = beg; c < end; c += 64) {
        int2 m = (c + lane < end) ? em[c + lane] : make_int2(0, 0);
        const int cnt = min(64, end - c);
        int k = 0;
        for (; k + 4 <= cnt; k += 4) {
#pragma unroll
            for (int j = 0; j < 4; ++j) {
                int s = __shfl(m.x, k + j, 64);
                float w = __int_as_float(__shfl(m.y, k + j, 64));
                unsigned u = Hb[(size_t)s * 64 + lane];
                acc.x += w * __uint_as_float(u << 16);
                acc.y += w * __uint_as_float(u & 0xffff0000u);
            }
        }
        for (; k < cnt; ++k) {
            int s = __shfl(m.x, k, 64);
            float w = __int_as_float(__shfl(m.y, k, 64));
            unsigned u = Hb[(size_t)s * 64 + lane];
            acc.x += w * __uint_as_float(u << 16);
            acc.y += w * __uint_as_float(u & 0xffff0000u);
        }
    }
    reinterpret_cast<float2*>(B + (size_t)node * DH)[lane] = acc;
}

// ---------------- gather aggregation (f32 H, 64 cols) ----------------
__global__ __launch_bounds__(256) void agg64_kernel(const float* __restrict__ H,
                                                    const int* __restrict__ rowptr,
                                                    const int2* __restrict__ em,
                                                    float* __restrict__ out) {
    const int node = blockIdx.x * 4 + (threadIdx.x >> 6);
    const int lane = threadIdx.x & 63;
    const int beg = rowptr[node];
    const int end = rowptr[node + 1];
    float acc = 0.f;
    for (int c = beg; c < end; c += 64) {
        int2 m = (c + lane < end) ? em[c + lane] : make_int2(0, 0);
        const int cnt = min(64, end - c);
        int k = 0;
        for (; k + 4 <= cnt; k += 4) {
#pragma unroll
            for (int j = 0; j < 4; ++j) {
                int s = __shfl(m.x, k + j, 64);
                float w = __int_as_float(__shfl(m.y, k + j, 64));
                acc += w * H[(size_t)s * DOUT + lane];
            }
        }
        for (; k < cnt; ++k) {
            int s = __shfl(m.x, k, 64);
            float w = __int_as_float(__shfl(m.y, k, 64));
            acc += w * H[(size_t)s * DOUT + lane];
        }
    }
    out[(size_t)node * DOUT + lane] = acc;
}

// ---------------- PairNorm stats ----------------
__global__ __launch_bounds__(256) void stats_kernel(const float* __restrict__ A,
                                                    float* __restrict__ colsum,
                                                    float* __restrict__ sumsq) {
    const int c = threadIdx.x & 127;
    const int rsub = threadIdx.x >> 7;
    float cs = 0.f, sq = 0.f;
    for (int r = blockIdx.x * 2 + rsub; r < N_NODES; r += gridDim.x * 2) {
        float v = A[(size_t)r * DH + c];
        cs += v;
        sq += v * v;
    }
    atomicAdd(&colsum[c], cs);
#pragma unroll
    for (int off = 32; off; off >>= 1) sq += __shfl_down(sq, off, 64);
    if ((threadIdx.x & 63) == 0) atomicAdd(sumsq, sq);
}

__global__ void finalize_stats(const float* __restrict__ colsum, const float* __restrict__ sumsq,
                               float* __restrict__ mu, float* __restrict__ inv) {
    const int t = threadIdx.x;  // 128 threads
    float m = colsum[t] / (float)N_NODES;
    mu[t] = m;
    float v = m * m;
    __shared__ float part[2];
#pragma unroll
    for (int off = 32; off; off >>= 1) v += __shfl_down(v, off, 64);
    if ((t & 63) == 0) part[t >> 6] = v;
    __syncthreads();
    if (t == 0) {
        float musq = part[0] + part[1];
        float s = (sumsq[0] - (float)N_NODES * musq) / (float)N_NODES;
        inv[0] = rsqrtf(EPS + s);
    }
}

extern "C" void kernel_launch(void* const* d_in, const int* in_sizes, int n_in,
                              void* d_out, int out_size, void* d_ws, size_t ws_size,
                              hipStream_t stream) {
    const float* x = (const float*)d_in[0];
    const int* edge_index = (const int*)d_in[1];
    const float* ew = (const float*)d_in[2];
    const float* W0 = (const float*)d_in[3];
    const float* b0 = (const float*)d_in[4];
    const float* W1 = (const float*)d_in[5];
    const float* b1 = (const float*)d_in[6];
    const float* Wout = (const float*)d_in[7];
    const float* bout = (const float*)d_in[8];

    const int* src = edge_index;
    const int* dst = edge_index + N_EDGES;
    float* out = (float*)d_out;

    // workspace layout (float units)
    float* base = (float*)d_ws;
    unsigned* Hb = (unsigned*)base;                  // N*64 uints (bf16 H) — aliased w/ HOUT
    float* HOUT = base;                              // N*64 f32 (output-layer H)
    float* B1 = base + (size_t)N_NODES * 64;         // N*128
    float* B2 = B1 + (size_t)N_NODES * DH;           // N*128
    int2* em = (int2*)(B2 + (size_t)N_NODES * DH);   // E int2
    int* counts = (int*)(em + N_EDGES);              // N
    int* rowptr = counts + N_NODES;                  // N+1
    int* fill = rowptr + N_NODES + 1;                // N
    // stats block, 16B aligned
    size_t soff = (size_t)(fill + N_NODES - (int*)base);
    soff = (soff + 3) & ~(size_t)3;
    float* stats = base + soff;
    float* colsum1 = stats;          // 128
    float* sumsq1 = stats + 128;     // 1 (+3 pad)
    float* colsum2 = stats + 132;    // 128
    float* sumsq2 = stats + 260;     // 1 (+3 pad)
    float* mu1 = stats + 264;        // 128
    float* inv1 = stats + 392;       // 1 (+3 pad)
    float* mu2 = stats + 396;        // 128
    float* inv2 = stats + 524;       // 1

    const int gemm_grid = (N_NODES + 63) / 64;
    const int agg_grid = N_NODES / 4;  // 25000, exact

    // ---- zero init (all up front) ----
    hipMemsetAsync(counts, 0, (size_t)N_NODES * sizeof(int), stream);
    hipMemsetAsync(fill, 0, (size_t)N_NODES * sizeof(int), stream);
    hipMemsetAsync(stats, 0, 261 * sizeof(float), stream);

    // ---- CSR build (dst-ordered) ----
    hist_kernel<<<2048, 256, 0, stream>>>(dst, counts);
    scan_kernel<<<1, 1024, 0, stream>>>(counts, rowptr);
    bucket_kernel<<<2048, 256, 0, stream>>>(src, dst, ew, rowptr, fill, em);

    // ---- Layer 1: Hb = bf16(x@W0+b0); B1 = gather(Hb); stats1 ----
    gemm_kernel<128, 0, true><<<gemm_grid, 256, 0, stream>>>(
        x, nullptr, nullptr, nullptr, nullptr, nullptr, W0, b0, Hb, N_NODES);
    agg128b_kernel<<<agg_grid, 256, 0, stream>>>(Hb, rowptr, em, B1);
    stats_kernel<<<1024, 256, 0, stream>>>(B1, colsum1, sumsq1);
    finalize_stats<<<1, 128, 0, stream>>>(colsum1, sumsq1, mu1, inv1);

    // ---- Layer 2: Hb = bf16(relu(pn1(B1))@W1+b1); B2 = gather(Hb); stats2 ----
    gemm_kernel<128, 1, true><<<gemm_grid, 256, 0, stream>>>(
        B1, mu1, inv1, nullptr, nullptr, nullptr, W1, b1, Hb, N_NODES);
    agg128b_kernel<<<agg_grid, 256, 0, stream>>>(Hb, rowptr, em, B2);
    stats_kernel<<<1024, 256, 0, stream>>>(B2, colsum2, sumsq2);
    finalize_stats<<<1, 128, 0, stream>>>(colsum2, sumsq2, mu2, inv2);

    // ---- Output: HOUT = (relu(pn2(B2))+relu(pn1(B1)))@Wout+bout; out = gather(HOUT) ----
    gemm_kernel<64, 2, false><<<gemm_grid, 256, 0, stream>>>(
        B2, mu2, inv2, B1, mu1, inv1, Wout, bout, HOUT, N_NODES);
    agg64_kernel<<<agg_grid, 256, 0, stream>>>(HOUT, rowptr, em, out);
}

// Round 4
// 615.194 us; speedup vs baseline: 11.6177x; 1.2924x over previous
//
#include <hip/hip_runtime.h>

#define N_NODES 100000
#define N_EDGES 1600000
#define DH 128
#define DOUT 64
#define EPS 1e-6f
#define NBINS 8
#define BINW 12500  // ceil(N_NODES / NBINS)
#define NREP 64     // stats replica buffers

__device__ inline unsigned bfround(float f) {  // f32 -> bf16 bits, round-nearest-even
    unsigned u = __float_as_uint(f);
    return (u + 0x7fffu + ((u >> 16) & 1u)) >> 16;
}
__device__ inline unsigned pack2(float a, float b) { return bfround(a) | (bfround(b) << 16); }

// ---------------- GEMM: Y[nrows, COLS] = f(X)[nrows,128] @ W[128,COLS] + b ----------------
// PN=0: f(X)=Xa.  PN=1: f(X)=relu((Xa-muA)*invA).  PN=2: ...+relu((Xb-muB)*invB)
template <int COLS, int PN, bool OUTBF>
__global__ __launch_bounds__(256) void gemm_kernel(const float* __restrict__ Xa,
                                                   const float* __restrict__ muA,
                                                   const float* __restrict__ invA,
                                                   const float* __restrict__ Xb,
                                                   const float* __restrict__ muB,
                                                   const float* __restrict__ invB,
                                                   const float* __restrict__ W,
                                                   const float* __restrict__ bias,
                                                   void* __restrict__ Yv, int nrows) {
    constexpr int K = 128;
    constexpr int BK = 64;
    constexpr int COLG = COLS / 8;
    constexpr int ROWG = 256 / COLG;
    constexpr int RPT = 64 / ROWG;

    __shared__ float wlds[BK * COLS];
    __shared__ float xlds[64][BK + 1];

    const int tid = threadIdx.x;
    const int row0 = blockIdx.x * 64;

    const float sA = (PN >= 1) ? invA[0] : 0.f;
    const float sB = (PN == 2) ? invB[0] : 0.f;

    const int colg = tid % COLG;
    const int rowg = tid / COLG;
    const int c0 = colg * 8;
    const int r0 = rowg * RPT;

    float acc[RPT][8];
#pragma unroll
    for (int i = 0; i < RPT; ++i)
#pragma unroll
        for (int j = 0; j < 8; ++j) acc[i][j] = 0.f;

    for (int kb = 0; kb < K; kb += BK) {
        constexpr int WVEC = BK * COLS / 4;
        for (int i = tid; i < WVEC; i += 256) {
            int kr = i / (COLS / 4);
            int c4 = i % (COLS / 4);
            reinterpret_cast<float4*>(wlds)[i] =
                reinterpret_cast<const float4*>(W)[(size_t)(kb + kr) * (COLS / 4) + c4];
        }
        for (int i = tid; i < 64 * (BK / 4); i += 256) {
            int r = i / (BK / 4);
            int c4 = i % (BK / 4);
            int col4 = kb / 4 + c4;
            float4 v = make_float4(0.f, 0.f, 0.f, 0.f);
            if (row0 + r < nrows) {
                v = reinterpret_cast<const float4*>(Xa + (size_t)(row0 + r) * K)[col4];
                if constexpr (PN >= 1) {
                    float4 m = reinterpret_cast<const float4*>(muA)[col4];
                    v.x = fmaxf((v.x - m.x) * sA, 0.f);
                    v.y = fmaxf((v.y - m.y) * sA, 0.f);
                    v.z = fmaxf((v.z - m.z) * sA, 0.f);
                    v.w = fmaxf((v.w - m.w) * sA, 0.f);
                }
                if constexpr (PN == 2) {
                    float4 v2 = reinterpret_cast<const float4*>(Xb + (size_t)(row0 + r) * K)[col4];
                    float4 m2 = reinterpret_cast<const float4*>(muB)[col4];
                    v.x += fmaxf((v2.x - m2.x) * sB, 0.f);
                    v.y += fmaxf((v2.y - m2.y) * sB, 0.f);
                    v.z += fmaxf((v2.z - m2.z) * sB, 0.f);
                    v.w += fmaxf((v2.w - m2.w) * sB, 0.f);
                }
            }
            xlds[r][c4 * 4 + 0] = v.x;
            xlds[r][c4 * 4 + 1] = v.y;
            xlds[r][c4 * 4 + 2] = v.z;
            xlds[r][c4 * 4 + 3] = v.w;
        }
        __syncthreads();

        for (int k = 0; k < BK; ++k) {
            float4 w0 = *reinterpret_cast<const float4*>(&wlds[k * COLS + c0]);
            float4 w1 = *reinterpret_cast<const float4*>(&wlds[k * COLS + c0 + 4]);
#pragma unroll
            for (int i = 0; i < RPT; ++i) {
                float xv = xlds[r0 + i][k];
                acc[i][0] += xv * w0.x;
                acc[i][1] += xv * w0.y;
                acc[i][2] += xv * w0.z;
                acc[i][3] += xv * w0.w;
                acc[i][4] += xv * w1.x;
                acc[i][5] += xv * w1.y;
                acc[i][6] += xv * w1.z;
                acc[i][7] += xv * w1.w;
            }
        }
        __syncthreads();
    }

    float bv[8];
#pragma unroll
    for (int j = 0; j < 8; ++j) bv[j] = bias[c0 + j];

#pragma unroll
    for (int i = 0; i < RPT; ++i) {
        int row = row0 + r0 + i;
        if (row < nrows) {
#pragma unroll
            for (int j = 0; j < 8; ++j) acc[i][j] += bv[j];
            if constexpr (OUTBF) {
                uint4 q;
                q.x = pack2(acc[i][0], acc[i][1]);
                q.y = pack2(acc[i][2], acc[i][3]);
                q.z = pack2(acc[i][4], acc[i][5]);
                q.w = pack2(acc[i][6], acc[i][7]);
                *reinterpret_cast<uint4*>((unsigned*)Yv + ((size_t)row * COLS + c0) / 2) = q;
            } else {
                float4 o0 = make_float4(acc[i][0], acc[i][1], acc[i][2], acc[i][3]);
                float4 o1 = make_float4(acc[i][4], acc[i][5], acc[i][6], acc[i][7]);
                float4* yp = reinterpret_cast<float4*>((float*)Yv + (size_t)row * COLS + c0);
                yp[0] = o0;
                yp[1] = o1;
            }
        }
    }
}

// ---------------- CSR build ----------------
__global__ __launch_bounds__(256) void hist_kernel(const int* __restrict__ dst,
                                                   int* __restrict__ counts) {
    int e = blockIdx.x * blockDim.x + threadIdx.x;
    const int stride = gridDim.x * blockDim.x;
    for (; e < N_EDGES; e += stride) atomicAdd(&counts[dst[e]], 1);
}

// single-block scan, int4-widened: 4096 elems per iteration
__global__ __launch_bounds__(1024) void scan_kernel(const int* __restrict__ counts,
                                                    int* __restrict__ rowptr) {
    __shared__ int wsum[16];
    const int tid = threadIdx.x;
    const int lane = tid & 63;
    const int w = tid >> 6;
    int offset = 0;
    if (tid == 0) rowptr[0] = 0;
    for (int base = 0; base < N_NODES; base += 4096) {
        int i = base + tid * 4;
        int4 v = make_int4(0, 0, 0, 0);
        if (i < N_NODES) v = *reinterpret_cast<const int4*>(counts + i);
        int p0 = v.x, p1 = p0 + v.y, p2 = p1 + v.z, p3 = p2 + v.w;
        int incl = p3;
#pragma unroll
        for (int d = 1; d < 64; d <<= 1) {
            int t = __shfl_up(incl, d, 64);
            if (lane >= d) incl += t;
        }
        if (lane == 63) wsum[w] = incl;
        __syncthreads();
        if (w == 0 && lane < 16) {
            int t = wsum[lane];
#pragma unroll
            for (int d = 1; d < 16; d <<= 1) {
                int u = __shfl_up(t, d, 64);
                if (lane >= d) t += u;
            }
            wsum[lane] = t;
        }
        __syncthreads();
        int woff = (w == 0) ? 0 : wsum[w - 1];
        int chunk_total = wsum[15];
        int tbase = offset + woff + incl - p3;  // exclusive prefix for this thread
        if (i < N_NODES) {
            rowptr[i + 1] = tbase + p0;
            rowptr[i + 2] = tbase + p1;
            rowptr[i + 3] = tbase + p2;
            rowptr[i + 4] = tbase + p3;
        }
        offset += chunk_total;
        __syncthreads();
    }
}

// XCD-binned bucket: block handles only dst in its bin -> em lines assembled in one L2
__global__ __launch_bounds__(256) void bucket_kernel(const int* __restrict__ src,
                                                     const int* __restrict__ dst,
                                                     const float* __restrict__ ew,
                                                     const int* __restrict__ rowptr,
                                                     int* __restrict__ fill,
                                                     int2* __restrict__ em) {
    const int myBin = blockIdx.x & (NBINS - 1);
    const int lo = myBin * BINW;
    const int hi = lo + BINW;
    int e = (blockIdx.x >> 3) * 256 + threadIdx.x;
    const int stride = (gridDim.x >> 3) * 256;
    for (; e < N_EDGES; e += stride) {
        int d = dst[e];
        if (d >= lo && d < hi) {
            int pos = atomicAdd(&fill[d], 1);
            em[rowptr[d] + pos] = make_int2(src[e], __float_as_int(ew[e]));
        }
    }
}

// ---------------- gather aggregation (bf16 H, 128 cols) + fused PairNorm stats ----------------
__global__ __launch_bounds__(256) void agg128b_kernel(const unsigned* __restrict__ Hb,
                                                      const int* __restrict__ rowptr,
                                                      const int2* __restrict__ em,
                                                      float* __restrict__ B,
                                                      float* __restrict__ cs_part,
                                                      float* __restrict__ ss_part) {
    __shared__ float cs[4][128];
    __shared__ float ssw[4];
    const int wv = threadIdx.x >> 6;
    const int lane = threadIdx.x & 63;
    const int node = blockIdx.x * 4 + wv;  // grid covers exactly N
    const int beg = rowptr[node];
    const int end = rowptr[node + 1];
    float2 acc = make_float2(0.f, 0.f);
    for (int c = beg; c < end; c += 64) {
        int2 m = (c + lane < end) ? em[c + lane] : make_int2(0, 0);
        const int cnt = min(64, end - c);
        int k = 0;
        for (; k + 4 <= cnt; k += 4) {
#pragma unroll
            for (int j = 0; j < 4; ++j) {
                int s = __shfl(m.x, k + j, 64);
                float w = __int_as_float(__shfl(m.y, k + j, 64));
                unsigned u = Hb[(size_t)s * 64 + lane];
                acc.x += w * __uint_as_float(u << 16);
                acc.y += w * __uint_as_float(u & 0xffff0000u);
            }
        }
        for (; k < cnt; ++k) {
            int s = __shfl(m.x, k, 64);
            float w = __int_as_float(__shfl(m.y, k, 64));
            unsigned u = Hb[(size_t)s * 64 + lane];
            acc.x += w * __uint_as_float(u << 16);
            acc.y += w * __uint_as_float(u & 0xffff0000u);
        }
    }
    reinterpret_cast<float2*>(B + (size_t)node * DH)[lane] = acc;

    // fused stats: per-block reduce then replica atomics
    cs[wv][lane * 2] = acc.x;
    cs[wv][lane * 2 + 1] = acc.y;
    float sq = acc.x * acc.x + acc.y * acc.y;
#pragma unroll
    for (int off = 32; off; off >>= 1) sq += __shfl_down(sq, off, 64);
    if (lane == 0) ssw[wv] = sq;
    __syncthreads();
    const int rep = blockIdx.x & (NREP - 1);
    if (threadIdx.x < 128) {
        float s = cs[0][threadIdx.x] + cs[1][threadIdx.x] + cs[2][threadIdx.x] + cs[3][threadIdx.x];
        atomicAdd(&cs_part[rep * 128 + threadIdx.x], s);
    }
    if (threadIdx.x == 0) atomicAdd(&ss_part[rep], ssw[0] + ssw[1] + ssw[2] + ssw[3]);
}

// ---------------- gather aggregation (f32 H, 64 cols) ----------------
__global__ __launch_bounds__(256) void agg64_kernel(const float* __restrict__ H,
                                                    const int* __restrict__ rowptr,
                                                    const int2* __restrict__ em,
                                                    float* __restrict__ out) {
    const int node = blockIdx.x * 4 + (threadIdx.x >> 6);
    const int lane = threadIdx.x & 63;
    const int beg = rowptr[node];
    const int end = rowptr[node + 1];
    float acc = 0.f;
    for (int c = beg; c < end; c += 64) {
        int2 m = (c + lane < end) ? em[c + lane] : make_int2(0, 0);
        const int cnt = min(64, end - c);
        int k = 0;
        for (; k + 4 <= cnt; k += 4) {
#pragma unroll
            for (int j = 0; j < 4; ++j) {
                int s = __shfl(m.x, k + j, 64);
                float w = __int_as_float(__shfl(m.y, k + j, 64));
                acc += w * H[(size_t)s * DOUT + lane];
            }
        }
        for (; k < cnt; ++k) {
            int s = __shfl(m.x, k, 64);
            float w = __int_as_float(__shfl(m.y, k, 64));
            acc += w * H[(size_t)s * DOUT + lane];
        }
    }
    out[(size_t)node * DOUT + lane] = acc;
}

// ---------------- finalize: reduce replicas -> mu, inv ----------------
__global__ void finalize_stats(const float* __restrict__ cs_part,
                               const float* __restrict__ ss_part, float* __restrict__ mu,
                               float* __restrict__ inv) {
    const int t = threadIdx.x;  // 128 threads
    float m = 0.f;
    for (int r = 0; r < NREP; ++r) m += cs_part[r * 128 + t];
    float mean = m / (float)N_NODES;
    mu[t] = mean;
    float v = mean * mean;
    __shared__ float partl[2];
    __shared__ float sstot;
#pragma unroll
    for (int off = 32; off; off >>= 1) v += __shfl_down(v, off, 64);
    if ((t & 63) == 0) partl[t >> 6] = v;
    float ss = (t < NREP) ? ss_part[t] : 0.f;
#pragma unroll
    for (int off = 32; off; off >>= 1) ss += __shfl_down(ss, off, 64);
    if (t == 0) sstot = ss;
    __syncthreads();
    if (t == 0) {
        float musq = partl[0] + partl[1];
        float s = (sstot - (float)N_NODES * musq) / (float)N_NODES;
        inv[0] = rsqrtf(EPS + s);
    }
}

extern "C" void kernel_launch(void* const* d_in, const int* in_sizes, int n_in,
                              void* d_out, int out_size, void* d_ws, size_t ws_size,
                              hipStream_t stream) {
    const float* x = (const float*)d_in[0];
    const int* edge_index = (const int*)d_in[1];
    const float* ew = (const float*)d_in[2];
    const float* W0 = (const float*)d_in[3];
    const float* b0 = (const float*)d_in[4];
    const float* W1 = (const float*)d_in[5];
    const float* b1 = (const float*)d_in[6];
    const float* Wout = (const float*)d_in[7];
    const float* bout = (const float*)d_in[8];

    const int* src = edge_index;
    const int* dst = edge_index + N_EDGES;
    float* out = (float*)d_out;

    // workspace layout
    float* base = (float*)d_ws;
    unsigned* Hb = (unsigned*)base;               // N*64 uints (bf16 H), aliased with HOUT
    float* HOUT = base;                           // N*64 f32
    float* B1 = base + (size_t)N_NODES * 64;      // N*128
    float* B2 = B1 + (size_t)N_NODES * DH;        // N*128
    int2* em = (int2*)(B2 + (size_t)N_NODES * DH);  // E int2 (16B-aligned)
    int* counts = (int*)(em + N_EDGES);           // N
    int* fill = counts + N_NODES;                 // N  (adjacent to counts: one memset)
    int* rowptr = fill + N_NODES;                 // N+1
    size_t soff = (size_t)(rowptr + N_NODES + 1 - (int*)base);
    soff = (soff + 3) & ~(size_t)3;
    float* stats = base + soff;
    float* cs_part1 = stats;                      // NREP*128
    float* ss_part1 = cs_part1 + NREP * 128;      // NREP
    float* cs_part2 = ss_part1 + NREP;            // NREP*128
    float* ss_part2 = cs_part2 + NREP * 128;      // NREP
    float* mu1 = ss_part2 + NREP;                 // 128
    float* inv1 = mu1 + 128;                      // 1 (+3 pad)
    float* mu2 = inv1 + 4;                        // 128
    float* inv2 = mu2 + 128;                      // 1

    const int gemm_grid = (N_NODES + 63) / 64;
    const int agg_grid = N_NODES / 4;  // 25000 exact

    // zero init
    hipMemsetAsync(counts, 0, (size_t)2 * N_NODES * sizeof(int), stream);  // counts + fill
    hipMemsetAsync(stats, 0, (size_t)2 * (NREP * 128 + NREP) * sizeof(float), stream);

    // CSR build (dst-ordered)
    hist_kernel<<<2048, 256, 0, stream>>>(dst, counts);
    scan_kernel<<<1, 1024, 0, stream>>>(counts, rowptr);
    bucket_kernel<<<2048, 256, 0, stream>>>(src, dst, ew, rowptr, fill, em);

    // Layer 1
    gemm_kernel<128, 0, true><<<gemm_grid, 256, 0, stream>>>(
        x, nullptr, nullptr, nullptr, nullptr, nullptr, W0, b0, Hb, N_NODES);
    agg128b_kernel<<<agg_grid, 256, 0, stream>>>(Hb, rowptr, em, B1, cs_part1, ss_part1);
    finalize_stats<<<1, 128, 0, stream>>>(cs_part1, ss_part1, mu1, inv1);

    // Layer 2
    gemm_kernel<128, 1, true><<<gemm_grid, 256, 0, stream>>>(
        B1, mu1, inv1, nullptr, nullptr, nullptr, W1, b1, Hb, N_NODES);
    agg128b_kernel<<<agg_grid, 256, 0, stream>>>(Hb, rowptr, em, B2, cs_part2, ss_part2);
    finalize_stats<<<1, 128, 0, stream>>>(cs_part2, ss_part2, mu2, inv2);

    // Output layer
    gemm_kernel<64, 2, false><<<gemm_grid, 256, 0, stream>>>(
        B2, mu2, inv2, B1, mu1, inv1, Wout, bout, HOUT, N_NODES);
    agg64_kernel<<<agg_grid, 256, 0, stream>>>(HOUT, rowptr, em, out);
}